// Round 1
// baseline (105.904 us; speedup 1.0000x reference)
//
#include <hip/hip_runtime.h>
#include <hip/hip_bf16.h>

#define A_NUM   256
#define D_DIM   256
#define N_TOT   4096
#define N_ANCH  256
#define NSPLIT  8
#define ANCH_PER_SPLIT (N_ANCH / NSPLIT)   // 32
#define INV_T   14.285714285714286f        // 1/0.07

typedef __attribute__((ext_vector_type(8))) short bf16x8;
typedef __attribute__((ext_vector_type(4))) float f32x4;

__device__ __forceinline__ ushort f2bf(float f) {
    union { float f; unsigned u; } a; a.f = f;
    unsigned u = a.u;
    u = (u + 0x7FFFu + ((u >> 16) & 1u)) >> 16;   // RNE
    return (ushort)u;
}

// ---------- kernel 0: fp32 -> bf16 conversion (X is feats flat, anchor-major) ----------
__global__ void __launch_bounds__(256) k_convert(const float* __restrict__ feats,
                                                 ushort* __restrict__ xb) {
    int idx = blockIdx.x * 256 + threadIdx.x;     // 262144 threads, 4 elems each
    int base = idx * 4;
    float4 v = *(const float4*)(feats + base);
    ushort4 o;
    o.x = f2bf(v.x); o.y = f2bf(v.y); o.z = f2bf(v.z); o.w = f2bf(v.w);
    *(ushort4*)(xb + base) = o;
}

// ---------- kernel 1: fused GEMM + row reductions (S_all, S_pos, P) ----------
__global__ void __launch_bounds__(64) k_pass1(const ushort* __restrict__ xb,
                                              const int* __restrict__ labels,
                                              float* __restrict__ partAll,
                                              float* __restrict__ partPos,
                                              float* __restrict__ partP) {
    int rt   = blockIdx.x >> 3;     // row anchor tile 0..255 (16 rows each)
    int sp   = blockIdx.x & 7;      // column split
    int lane = threadIdx.x;
    int lrow  = lane & 15;          // A-row / B-col / C-col index within tile
    int khalf = lane >> 4;          // k-subblock

    // A panel (16 rows x 256 k) held in registers for the whole sweep
    bf16x8 a[8];
    const ushort* arow = xb + (rt * 16 + lrow) * D_DIM + khalf * 8;
#pragma unroll
    for (int ks = 0; ks < 8; ++ks)
        a[ks] = *(const bf16x8*)(arow + ks * 32);

    int myLab = labels[rt];

    float accAll[4] = {0,0,0,0}, accPos[4] = {0,0,0,0}, accP[4] = {0,0,0,0};

    int aj0 = sp * ANCH_PER_SPLIT;
    for (int aj = aj0; aj < aj0 + ANCH_PER_SPLIT; ++aj) {
        const ushort* brow = xb + (aj * 16 + lrow) * D_DIM + khalf * 8;
        f32x4 c = {0.f, 0.f, 0.f, 0.f};
#pragma unroll
        for (int ks = 0; ks < 8; ++ks) {
            bf16x8 b = *(const bf16x8*)(brow + ks * 32);
            c = __builtin_amdgcn_mfma_f32_16x16x32_bf16(a[ks], b, c, 0, 0, 0);
        }
        bool pos = (labels[aj] == myLab);      // wave-uniform
        bool diagTile = (aj == rt);
#pragma unroll
        for (int i = 0; i < 4; ++i) {
            // element: global row = rt*16 + khalf*4 + i, global col = aj*16 + lrow
            float l = c[i] * INV_T - INV_T;    // logits - 1/T  (shift-invariant)
            float e = __expf(l);
            accAll[i] += e;
            if (pos) {
                accPos[i] += e;                 // includes diagonal (cancels in ns)
                if (!(diagTile && (khalf * 4 + i) == lrow))
                    accP[i] += l;               // positive logit sum, excl. diagonal
            }
        }
    }

    // reduce across the 16-lane column groups
#pragma unroll
    for (int m = 1; m < 16; m <<= 1) {
#pragma unroll
        for (int i = 0; i < 4; ++i) {
            accAll[i] += __shfl_xor(accAll[i], m, 64);
            accPos[i] += __shfl_xor(accPos[i], m, 64);
            accP[i]   += __shfl_xor(accP[i],   m, 64);
        }
    }
    if (lrow == 0) {
#pragma unroll
        for (int i = 0; i < 4; ++i) {
            int row = rt * 16 + khalf * 4 + i;
            partAll[sp * N_TOT + row] = accAll[i];
            partPos[sp * N_TOT + row] = accPos[i];
            partP[sp * N_TOT + row]   = accP[i];
        }
    }
}

// ---------- kernel 2: combine column-split partials ----------
__global__ void __launch_bounds__(256) k_combine(const float* __restrict__ partAll,
                                                 const float* __restrict__ partPos,
                                                 const float* __restrict__ partP,
                                                 float* __restrict__ ns,
                                                 float* __restrict__ P) {
    int row = blockIdx.x * 256 + threadIdx.x;   // 4096 threads
    float sAll = 0.f, sPos = 0.f, sP = 0.f;
#pragma unroll
    for (int s = 0; s < NSPLIT; ++s) {
        sAll += partAll[s * N_TOT + row];
        sPos += partPos[s * N_TOT + row];
        sP   += partP[s * N_TOT + row];
    }
    ns[row] = sAll - sPos;   // negative-pair exp sum
    P[row]  = sP;
}

// ---------- kernel 3: positive-pair pass, L = sum log(exp(l) + ns) ----------
__global__ void __launch_bounds__(64) k_passB(const ushort* __restrict__ xb,
                                              const int* __restrict__ labels,
                                              const float* __restrict__ ns,
                                              float* __restrict__ Lout) {
    int rt   = blockIdx.x;
    int lane = threadIdx.x;
    int lrow  = lane & 15;
    int khalf = lane >> 4;

    bf16x8 a[8];
    const ushort* arow = xb + (rt * 16 + lrow) * D_DIM + khalf * 8;
#pragma unroll
    for (int ks = 0; ks < 8; ++ks)
        a[ks] = *(const bf16x8*)(arow + ks * 32);

    int myLab = labels[rt];
    float nsr[4];
#pragma unroll
    for (int i = 0; i < 4; ++i) nsr[i] = ns[rt * 16 + khalf * 4 + i];

    float accL[4] = {0,0,0,0};
    for (int aj = 0; aj < N_ANCH; ++aj) {
        if (labels[aj] != myLab) continue;      // only positive tiles (~5%)
        const ushort* brow = xb + (aj * 16 + lrow) * D_DIM + khalf * 8;
        f32x4 c = {0.f, 0.f, 0.f, 0.f};
#pragma unroll
        for (int ks = 0; ks < 8; ++ks) {
            bf16x8 b = *(const bf16x8*)(brow + ks * 32);
            c = __builtin_amdgcn_mfma_f32_16x16x32_bf16(a[ks], b, c, 0, 0, 0);
        }
        bool diagTile = (aj == rt);
#pragma unroll
        for (int i = 0; i < 4; ++i) {
            float l = c[i] * INV_T - INV_T;
            if (!(diagTile && (khalf * 4 + i) == lrow))
                accL[i] += __logf(__expf(l) + nsr[i]);
        }
    }
#pragma unroll
    for (int m = 1; m < 16; m <<= 1) {
#pragma unroll
        for (int i = 0; i < 4; ++i)
            accL[i] += __shfl_xor(accL[i], m, 64);
    }
    if (lrow == 0) {
#pragma unroll
        for (int i = 0; i < 4; ++i)
            Lout[rt * 16 + khalf * 4 + i] = accL[i];
    }
}

// ---------- kernel 4: final deterministic reduction ----------
__global__ void __launch_bounds__(256) k_finalize(const int* __restrict__ labels,
                                                  const float* __restrict__ P,
                                                  const float* __restrict__ L,
                                                  float* __restrict__ out) {
    __shared__ int cnt[32];
    __shared__ float red[256];
    int t = threadIdx.x;
    if (t < 32) cnt[t] = 0;
    __syncthreads();
    atomicAdd(&cnt[labels[t]], 1);      // t = anchor id (256 anchors, 256 threads)
    __syncthreads();
    float s = 0.f;
    for (int row = t; row < N_TOT; row += 256) {
        int np = 16 * cnt[labels[row >> 4]] - 1;   // sum(pos_mask) per row
        s += (P[row] - L[row]) / (float)np;
    }
    red[t] = s;
    __syncthreads();
    for (int off = 128; off; off >>= 1) {
        if (t < off) red[t] += red[t + off];
        __syncthreads();
    }
    if (t == 0) out[0] = -red[0] / (float)N_TOT;
}

extern "C" void kernel_launch(void* const* d_in, const int* in_sizes, int n_in,
                              void* d_out, int out_size, void* d_ws, size_t ws_size,
                              hipStream_t stream) {
    const float* feats  = (const float*)d_in[0];
    const int*   labels = (const int*)d_in[1];
    float* out = (float*)d_out;

    char* ws = (char*)d_ws;
    ushort* xb     = (ushort*)ws;                         // 2 MB
    float* partAll = (float*)(ws + 2 * 1024 * 1024);      // 8*4096 f32
    float* partPos = partAll + NSPLIT * N_TOT;
    float* partP   = partPos + NSPLIT * N_TOT;
    float* ns      = partP   + NSPLIT * N_TOT;
    float* P       = ns + N_TOT;
    float* L       = P  + N_TOT;

    k_convert <<<1024, 256, 0, stream>>>(feats, xb);
    k_pass1   <<<N_ANCH * NSPLIT, 64, 0, stream>>>(xb, labels, partAll, partPos, partP);
    k_combine <<<N_TOT / 256, 256, 0, stream>>>(partAll, partPos, partP, ns, P);
    k_passB   <<<N_ANCH, 64, 0, stream>>>(xb, labels, ns, L);
    k_finalize<<<1, 256, 0, stream>>>(labels, P, L, out);
}

// Round 2
// 80.308 us; speedup vs baseline: 1.3187x; 1.3187x over previous
//
#include <hip/hip_runtime.h>
#include <hip/hip_bf16.h>

#define D_DIM   256
#define N_TOT   4096
#define N_ANCH  256
#define NSPLIT  16                     // pass1 column splits
#define COLS_PER (N_ANCH / NSPLIT)     // 16
#define NSPLITB 8                      // passB column splits
#define COLS_PER_B (N_ANCH / NSPLITB)  // 32
#define K1  20.60992915555662f         // (1/0.07) * log2(e)
#define LN2 0.6931471805599453f

typedef __attribute__((ext_vector_type(8))) short bf16x8;
typedef __attribute__((ext_vector_type(4))) float f32x4;

#define MFMA(a, b, c) __builtin_amdgcn_mfma_f32_16x16x32_bf16((a), (b), (c), 0, 0, 0)

__device__ __forceinline__ ushort f2bf(float f) {
    union { float f; unsigned u; } a; a.f = f;
    unsigned u = a.u;
    u = (u + 0x7FFFu + ((u >> 16) & 1u)) >> 16;   // RNE
    return (ushort)u;
}

// ---------- kernel 0: fp32 -> bf16 ----------
__global__ void __launch_bounds__(256) k_convert(const float* __restrict__ feats,
                                                 ushort* __restrict__ xb) {
    int idx = blockIdx.x * 256 + threadIdx.x;
    int base = idx * 4;
    float4 v = *(const float4*)(feats + base);
    ushort4 o;
    o.x = f2bf(v.x); o.y = f2bf(v.y); o.z = f2bf(v.z); o.w = f2bf(v.w);
    *(ushort4*)(xb + base) = o;
}

// epilogue for one 16x16 tile result (4 elems/lane), accumulating in base-2 space
__device__ __forceinline__ void epi(const f32x4 c, bool pos, bool dt, int lrow, int khalf,
                                    float* aAll, float* aPos, float* aP) {
#pragma unroll
    for (int i = 0; i < 4; ++i) {
        float l2 = __builtin_fmaf(c[i], K1, -K1);   // log2-space shifted logit
        float e  = exp2f(l2);
        aAll[i] += e;
        if (pos) {                                   // wave-uniform branch
            aPos[i] += e;
            bool d = dt & ((khalf * 4 + i) == lrow); // self-contrast diagonal
            aP[i] += d ? 0.0f : l2;
        }
    }
}

// ---------- kernel 1: fused GEMM + row reductions ----------
// one wave per block; wave owns 2 row anchors (32 rows), sweeps 16 col anchors
__global__ void __launch_bounds__(64, 2) k_pass1(const ushort* __restrict__ xb,
                                                 const int* __restrict__ labels,
                                                 float* __restrict__ partAll,
                                                 float* __restrict__ partPos,
                                                 float* __restrict__ partP) {
    int r2   = blockIdx.x >> 4;          // row pair 0..127
    int sp   = blockIdx.x & (NSPLIT - 1);
    int lane = threadIdx.x;
    int lrow  = lane & 15;
    int khalf = lane >> 4;
    int rt0 = r2 * 2, rt1 = rt0 + 1;

    bf16x8 a0[8], a1[8];                 // A panels: 2 anchors x 256 k, resident
    const ushort* ar0 = xb + (rt0 * 16 + lrow) * D_DIM + khalf * 8;
    const ushort* ar1 = ar0 + 16 * D_DIM;
#pragma unroll
    for (int ks = 0; ks < 8; ++ks) {
        a0[ks] = *(const bf16x8*)(ar0 + ks * 32);
        a1[ks] = *(const bf16x8*)(ar1 + ks * 32);
    }
    int lab0 = labels[rt0], lab1 = labels[rt1];

    float accAll0[4] = {0,0,0,0}, accPos0[4] = {0,0,0,0}, accP0[4] = {0,0,0,0};
    float accAll1[4] = {0,0,0,0}, accPos1[4] = {0,0,0,0}, accP1[4] = {0,0,0,0};

    int base = sp * COLS_PER;
    for (int j = 0; j < COLS_PER; j += 2) {          // 2 col anchors per step
        int aj0 = base + j, aj1 = aj0 + 1;
        const ushort* bp0 = xb + (aj0 * 16 + lrow) * D_DIM + khalf * 8;
        const ushort* bp1 = bp0 + 16 * D_DIM;
        bf16x8 b0[8], b1[8];
#pragma unroll
        for (int ks = 0; ks < 8; ++ks) {
            b0[ks] = *(const bf16x8*)(bp0 + ks * 32);
            b1[ks] = *(const bf16x8*)(bp1 + ks * 32);
        }
        f32x4 c00 = {0,0,0,0}, c01 = {0,0,0,0}, c10 = {0,0,0,0}, c11 = {0,0,0,0};
#pragma unroll
        for (int ks = 0; ks < 8; ++ks) {             // 4 independent MFMA chains
            c00 = MFMA(a0[ks], b0[ks], c00);
            c10 = MFMA(a1[ks], b0[ks], c10);
            c01 = MFMA(a0[ks], b1[ks], c01);
            c11 = MFMA(a1[ks], b1[ks], c11);
        }
        int cl0 = labels[aj0], cl1 = labels[aj1];
        epi(c00, cl0 == lab0, aj0 == rt0, lrow, khalf, accAll0, accPos0, accP0);
        epi(c10, cl0 == lab1, aj0 == rt1, lrow, khalf, accAll1, accPos1, accP1);
        epi(c01, cl1 == lab0, aj1 == rt0, lrow, khalf, accAll0, accPos0, accP0);
        epi(c11, cl1 == lab1, aj1 == rt1, lrow, khalf, accAll1, accPos1, accP1);
    }

#pragma unroll
    for (int m = 1; m < 16; m <<= 1) {               // reduce over 16-lane col groups
#pragma unroll
        for (int i = 0; i < 4; ++i) {
            accAll0[i] += __shfl_xor(accAll0[i], m, 64);
            accPos0[i] += __shfl_xor(accPos0[i], m, 64);
            accP0[i]   += __shfl_xor(accP0[i],   m, 64);
            accAll1[i] += __shfl_xor(accAll1[i], m, 64);
            accPos1[i] += __shfl_xor(accPos1[i], m, 64);
            accP1[i]   += __shfl_xor(accP1[i],   m, 64);
        }
    }
    if (lrow == 0) {
#pragma unroll
        for (int i = 0; i < 4; ++i) {
            int row0 = rt0 * 16 + khalf * 4 + i;
            int row1 = row0 + 16;
            partAll[row0 * NSPLIT + sp] = accAll0[i];
            partPos[row0 * NSPLIT + sp] = accPos0[i];
            partP[row0 * NSPLIT + sp]   = accP0[i];
            partAll[row1 * NSPLIT + sp] = accAll1[i];
            partPos[row1 * NSPLIT + sp] = accPos1[i];
            partP[row1 * NSPLIT + sp]   = accP1[i];
        }
    }
}

// ---------- kernel 2: positive-pair pass, partL = sum log2(exp2(l2) + ns) ----------
__global__ void __launch_bounds__(64, 2) k_passB(const ushort* __restrict__ xb,
                                                 const int* __restrict__ labels,
                                                 const float* __restrict__ partAll,
                                                 const float* __restrict__ partPos,
                                                 float* __restrict__ partL) {
    int r2   = blockIdx.x >> 3;          // row pair 0..127
    int sp   = blockIdx.x & (NSPLITB - 1);
    int lane = threadIdx.x;
    int lrow  = lane & 15;
    int khalf = lane >> 4;
    int rt0 = r2 * 2, rt1 = rt0 + 1;

    // compute ns (negative exp sum) for our 32 rows from pass1 partials
    __shared__ float nsS[32];
    {
        int rowLocal = lane >> 1;        // 0..31
        int half = lane & 1;             // 8 splits each
        const float* pa = partAll + (r2 * 32 + rowLocal) * NSPLIT + half * 8;
        const float* pp = partPos + (r2 * 32 + rowLocal) * NSPLIT + half * 8;
        float4 A0 = *(const float4*)pa, A1 = *(const float4*)(pa + 4);
        float4 P0 = *(const float4*)pp, P1 = *(const float4*)(pp + 4);
        float s = (A0.x + A0.y + A0.z + A0.w + A1.x + A1.y + A1.z + A1.w)
                - (P0.x + P0.y + P0.z + P0.w + P1.x + P1.y + P1.z + P1.w);
        s += __shfl_xor(s, 1, 64);
        if (half == 0) nsS[rowLocal] = s;
    }
    __syncthreads();
    float ns0[4], ns1[4];
#pragma unroll
    for (int i = 0; i < 4; ++i) {
        ns0[i] = nsS[khalf * 4 + i];
        ns1[i] = nsS[16 + khalf * 4 + i];
    }

    bf16x8 a0[8], a1[8];
    const ushort* ar0 = xb + (rt0 * 16 + lrow) * D_DIM + khalf * 8;
    const ushort* ar1 = ar0 + 16 * D_DIM;
#pragma unroll
    for (int ks = 0; ks < 8; ++ks) {
        a0[ks] = *(const bf16x8*)(ar0 + ks * 32);
        a1[ks] = *(const bf16x8*)(ar1 + ks * 32);
    }
    int lab0 = labels[rt0], lab1 = labels[rt1];

    float accL0[4] = {0,0,0,0}, accL1[4] = {0,0,0,0};
    int base = sp * COLS_PER_B;
    for (int aj = base; aj < base + COLS_PER_B; ++aj) {
        int cl = labels[aj];
        bool p0 = (cl == lab0), p1 = (cl == lab1);
        if (!(p0 | p1)) continue;        // wave-uniform skip (~89% of tiles)
        const ushort* bp = xb + (aj * 16 + lrow) * D_DIM + khalf * 8;
        bf16x8 b[8];
#pragma unroll
        for (int ks = 0; ks < 8; ++ks) b[ks] = *(const bf16x8*)(bp + ks * 32);
        f32x4 c0 = {0,0,0,0}, c1 = {0,0,0,0};
#pragma unroll
        for (int ks = 0; ks < 8; ++ks) {
            c0 = MFMA(a0[ks], b[ks], c0);
            c1 = MFMA(a1[ks], b[ks], c1);
        }
        if (p0) {
#pragma unroll
            for (int i = 0; i < 4; ++i) {
                float l2 = __builtin_fmaf(c0[i], K1, -K1);
                float lg = __log2f(exp2f(l2) + ns0[i]);
                bool d = (aj == rt0) & ((khalf * 4 + i) == lrow);
                accL0[i] += d ? 0.0f : lg;
            }
        }
        if (p1) {
#pragma unroll
            for (int i = 0; i < 4; ++i) {
                float l2 = __builtin_fmaf(c1[i], K1, -K1);
                float lg = __log2f(exp2f(l2) + ns1[i]);
                bool d = (aj == rt1) & ((khalf * 4 + i) == lrow);
                accL1[i] += d ? 0.0f : lg;
            }
        }
    }
#pragma unroll
    for (int m = 1; m < 16; m <<= 1) {
#pragma unroll
        for (int i = 0; i < 4; ++i) {
            accL0[i] += __shfl_xor(accL0[i], m, 64);
            accL1[i] += __shfl_xor(accL1[i], m, 64);
        }
    }
    if (lrow == 0) {
#pragma unroll
        for (int i = 0; i < 4; ++i) {
            int row0 = rt0 * 16 + khalf * 4 + i;
            int row1 = row0 + 16;
            partL[row0 * NSPLITB + sp] = accL0[i];
            partL[row1 * NSPLITB + sp] = accL1[i];
        }
    }
}

// ---------- kernel 3: final deterministic reduction ----------
__global__ void __launch_bounds__(256) k_finalize(const int* __restrict__ labels,
                                                  const float* __restrict__ partP,
                                                  const float* __restrict__ partL,
                                                  float* __restrict__ out) {
    __shared__ int cnt[32];
    __shared__ float red[256];
    int t = threadIdx.x;
    if (t < 32) cnt[t] = 0;
    __syncthreads();
    atomicAdd(&cnt[labels[t]], 1);       // t = anchor id
    __syncthreads();
    float s = 0.f;
    for (int row = t; row < N_TOT; row += 256) {
        const float4* pp = (const float4*)(partP + row * NSPLIT);
        float P2 = 0.f;
#pragma unroll
        for (int q = 0; q < 4; ++q) { float4 v = pp[q]; P2 += v.x + v.y + v.z + v.w; }
        const float4* pl = (const float4*)(partL + row * NSPLITB);
        float L2 = 0.f;
#pragma unroll
        for (int q = 0; q < 2; ++q) { float4 v = pl[q]; L2 += v.x + v.y + v.z + v.w; }
        int np = 16 * cnt[labels[row >> 4]] - 1;
        s += (P2 - L2) / (float)np;
    }
    red[t] = s;
    __syncthreads();
    for (int off = 128; off; off >>= 1) {
        if (t < off) red[t] += red[t + off];
        __syncthreads();
    }
    if (t == 0) out[0] = -red[0] * (LN2 / (float)N_TOT);
}

extern "C" void kernel_launch(void* const* d_in, const int* in_sizes, int n_in,
                              void* d_out, int out_size, void* d_ws, size_t ws_size,
                              hipStream_t stream) {
    const float* feats  = (const float*)d_in[0];
    const int*   labels = (const int*)d_in[1];
    float* out = (float*)d_out;

    char* ws = (char*)d_ws;
    ushort* xb     = (ushort*)ws;                        // 2 MB
    float* partAll = (float*)(ws + 2 * 1024 * 1024);     // 4096*16 f32
    float* partPos = partAll + N_TOT * NSPLIT;
    float* partP   = partPos + N_TOT * NSPLIT;
    float* partL   = partP   + N_TOT * NSPLIT;           // 4096*8 f32

    k_convert <<<1024, 256, 0, stream>>>(feats, xb);
    k_pass1   <<<128 * NSPLIT,  64, 0, stream>>>(xb, labels, partAll, partPos, partP);
    k_passB   <<<128 * NSPLITB, 64, 0, stream>>>(xb, labels, partAll, partPos, partL);
    k_finalize<<<1, 256, 0, stream>>>(labels, partP, partL, out);
}

// Round 3
// 60.967 us; speedup vs baseline: 1.7371x; 1.3172x over previous
//
#include <hip/hip_runtime.h>
#include <hip/hip_bf16.h>

#define D_DIM   256
#define N_TOT   4096
#define N_ANCH  256
#define NSPLIT  32                    // pass1 column splits
#define COLS_PER 8                    // anchors per split
#define K1  20.60992915555662f        // (1/0.07) * log2(e)
#define LN2 0.6931471805599453f
#define MAXNP    48                   // max anchors per label (19 labels, mean 13.5)
#define MAXTILES 8192                 // max total positive tiles (expected ~3700)

typedef __attribute__((ext_vector_type(8))) short bf16x8;
typedef __attribute__((ext_vector_type(4))) float f32x4;

#define MFMA(a, b, c) __builtin_amdgcn_mfma_f32_16x16x32_bf16((a), (b), (c), 0, 0, 0)

__device__ __forceinline__ ushort f2bf(float f) {
    union { float f; unsigned u; } a; a.f = f;
    unsigned u = a.u;
    u = (u + 0x7FFFu + ((u >> 16) & 1u)) >> 16;   // RNE
    return (ushort)u;
}

// ---------- kernel 0: fp32 -> bf16 convert; block 0 also does label setup ----------
__global__ void __launch_bounds__(256) k_convert(const float* __restrict__ feats,
                                                 const int* __restrict__ labels,
                                                 ushort* __restrict__ xb,
                                                 int* __restrict__ cntW,
                                                 int* __restrict__ posRank,
                                                 int* __restrict__ tileOff) {
    int idx = blockIdx.x * 256 + threadIdx.x;
    int base = idx * 4;
    float4 v = *(const float4*)(feats + base);
    ushort4 o;
    o.x = f2bf(v.x); o.y = f2bf(v.y); o.z = f2bf(v.z); o.w = f2bf(v.w);
    *(ushort4*)(xb + base) = o;

    if (blockIdx.x == 0) {
        __shared__ int labS[N_ANCH];
        __shared__ int cntS[32];
        int t = threadIdx.x;
        if (t < 32) cntS[t] = 0;
        labS[t] = labels[t];
        __syncthreads();
        atomicAdd(&cntS[labS[t]], 1);
        __syncthreads();
        int myLab = labS[t];
        int rank = 0, toff = 0;
        for (int b = 0; b < t; ++b) {
            int lb = labS[b];
            rank += (lb == myLab);
            toff += cntS[lb];
        }
        posRank[t] = rank;
        tileOff[t] = toff;
        if (t < 32) cntW[t] = cntS[t];
    }
}

// ---------- kernel 1: fused GEMM sweep ----------
// 1024 blocks x 4 waves; wave owns 2 row anchors, sweeps 8 col anchors.
// Accumulates S_all per row; stores positive tiles (raw fp32 scores) to posBuf.
__global__ void __launch_bounds__(256, 3) k_pass1(const ushort* __restrict__ xb,
                                                  const int* __restrict__ labels,
                                                  const int* __restrict__ posRank,
                                                  const int* __restrict__ tileOff,
                                                  float* __restrict__ partAll,
                                                  float* __restrict__ posBuf) {
    int g = blockIdx.x >> 5;           // row group 0..31 (8 anchors each)
    int s = blockIdx.x & 31;           // col split 0..31 (8 anchors each)
    int wid  = threadIdx.x >> 6;
    int lane = threadIdx.x & 63;
    int lrow  = lane & 15;
    int khalf = lane >> 4;
    int rp  = g * 4 + wid;             // row pair 0..127
    int rt0 = rp * 2, rt1 = rt0 + 1;

    // A panels: 2 anchors x 256 k in registers, pinned against rematerialization
    bf16x8 a0[8], a1[8];
    const ushort* ar0 = xb + (rt0 * 16 + lrow) * D_DIM + khalf * 8;
    const ushort* ar1 = ar0 + 16 * D_DIM;
#pragma unroll
    for (int ks = 0; ks < 8; ++ks) {
        a0[ks] = *(const bf16x8*)(ar0 + ks * 32);
        a1[ks] = *(const bf16x8*)(ar1 + ks * 32);
    }
#pragma unroll
    for (int ks = 0; ks < 8; ++ks) {
        asm volatile("" : "+v"(a0[ks]), "+v"(a1[ks]));
    }

    int lab0 = labels[rt0], lab1 = labels[rt1];
    int off0 = tileOff[rt0], off1 = tileOff[rt1];

    int cbase = s * COLS_PER;
    int labc[COLS_PER], rankc[COLS_PER];
#pragma unroll
    for (int j = 0; j < COLS_PER; ++j) {
        labc[j]  = labels[cbase + j];
        rankc[j] = posRank[cbase + j];
    }

    float aAll0[4] = {0,0,0,0}, aAll1[4] = {0,0,0,0};

#pragma unroll
    for (int j = 0; j < COLS_PER; ++j) {
        int aj = cbase + j;
        const ushort* bp = xb + (aj * 16 + lrow) * D_DIM + khalf * 8;
        bf16x8 b[8];
#pragma unroll
        for (int ks = 0; ks < 8; ++ks) b[ks] = *(const bf16x8*)(bp + ks * 32);
        f32x4 c0 = {0,0,0,0}, c1 = {0,0,0,0};
#pragma unroll
        for (int ks = 0; ks < 8; ++ks) {
            c0 = MFMA(a0[ks], b[ks], c0);
            c1 = MFMA(a1[ks], b[ks], c1);
        }
#pragma unroll
        for (int i = 0; i < 4; ++i) {
            aAll0[i] += exp2f(__builtin_fmaf(c0[i], K1, -K1));
            aAll1[i] += exp2f(__builtin_fmaf(c1[i], K1, -K1));
        }
        if (labc[j] == lab0)    // wave-uniform; store raw scores for passB
            *(f32x4*)(posBuf + (size_t)(off0 + rankc[j]) * 256 + lane * 4) = c0;
        if (labc[j] == lab1)
            *(f32x4*)(posBuf + (size_t)(off1 + rankc[j]) * 256 + lane * 4) = c1;
    }

#pragma unroll
    for (int m = 1; m < 16; m <<= 1) {
#pragma unroll
        for (int i = 0; i < 4; ++i) {
            aAll0[i] += __shfl_xor(aAll0[i], m, 64);
            aAll1[i] += __shfl_xor(aAll1[i], m, 64);
        }
    }
    if (lrow == 0) {
#pragma unroll
        for (int i = 0; i < 4; ++i) {
            int r0 = rt0 * 16 + khalf * 4 + i;
            int r1 = r0 + 16;
            partAll[r0 * NSPLIT + s] = aAll0[i];
            partAll[r1 * NSPLIT + s] = aAll1[i];
        }
    }
}

// ---------- kernel 2: elementwise positive pass ----------
// block rt (256 blocks x 256 threads): S_pos + P from posBuf, ns = S_all - S_pos,
// then L = sum log2(2^l2 + ns); writes per-anchor partial of sum (P-L)/np_row.
__global__ void __launch_bounds__(256) k_passB(const float* __restrict__ posBuf,
                                               const int* __restrict__ labels,
                                               const int* __restrict__ cntW,
                                               const int* __restrict__ posRank,
                                               const int* __restrict__ tileOff,
                                               const float* __restrict__ partAll,
                                               float* __restrict__ partOut) {
    int rt  = blockIdx.x;
    int tid = threadIdx.x;
    int l = tid >> 2, i = tid & 3;
    int r   = (l >> 4) * 4 + i;        // row within tile (fixed per thread)
    int col = l & 15;

    int np       = cntW[labels[rt]];
    int off      = tileOff[rt];
    int selfRank = posRank[rt];

    __shared__ float tile[MAXNP * 256];
    __shared__ float shA[16][17];
    __shared__ float shB[16][17];
    __shared__ float nsSh[16], PSh[16];

    float sE = 0.f, sP = 0.f;
    const float* src = posBuf + (size_t)off * 256 + tid;
    for (int j = 0; j < np; ++j) {
        float c = src[j * 256];
        tile[j * 256 + tid] = c;
        float l2 = __builtin_fmaf(c, K1, -K1);
        sE += exp2f(l2);
        bool diag = (j == selfRank) & (col == r);
        sP += diag ? 0.f : l2;
    }
    shA[r][col] = sE;
    shB[r][col] = sP;
    __syncthreads();
    if (tid < 16) {
        float e = 0.f, p = 0.f;
#pragma unroll
        for (int cc = 0; cc < 16; ++cc) { e += shA[tid][cc]; p += shB[tid][cc]; }
        const float* pa = partAll + (rt * 16 + tid) * NSPLIT;
        float sall = 0.f;
#pragma unroll
        for (int q = 0; q < 8; ++q) {
            float4 v = *(const float4*)(pa + q * 4);
            sall += v.x + v.y + v.z + v.w;
        }
        nsSh[tid] = sall - e;          // negative-pair exp sum
        PSh[tid]  = p;
    }
    __syncthreads();

    float nsv = nsSh[r];
    float sL = 0.f;
    for (int j = 0; j < np; ++j) {
        float c  = tile[j * 256 + tid];
        float l2 = __builtin_fmaf(c, K1, -K1);
        float lg = __log2f(exp2f(l2) + nsv);
        bool diag = (j == selfRank) & (col == r);
        sL += diag ? 0.f : lg;
    }
    __syncthreads();
    shA[r][col] = sL;
    __syncthreads();
    if (tid < 16) {
        float L = 0.f;
#pragma unroll
        for (int cc = 0; cc < 16; ++cc) L += shA[tid][cc];
        float npRow = (float)(16 * np - 1);
        shB[0][tid] = (PSh[tid] - L) / npRow;
    }
    __syncthreads();
    if (tid == 0) {
        float s = 0.f;
#pragma unroll
        for (int q = 0; q < 16; ++q) s += shB[0][q];
        partOut[rt] = s;
    }
}

// ---------- kernel 3: final reduction ----------
__global__ void __launch_bounds__(256) k_final(const float* __restrict__ partOut,
                                               float* __restrict__ out) {
    __shared__ float red[256];
    int t = threadIdx.x;
    red[t] = partOut[t];
    __syncthreads();
    for (int o = 128; o; o >>= 1) {
        if (t < o) red[t] += red[t + o];
        __syncthreads();
    }
    if (t == 0) out[0] = -red[0] * (LN2 / (float)N_TOT);
}

extern "C" void kernel_launch(void* const* d_in, const int* in_sizes, int n_in,
                              void* d_out, int out_size, void* d_ws, size_t ws_size,
                              hipStream_t stream) {
    const float* feats  = (const float*)d_in[0];
    const int*   labels = (const int*)d_in[1];
    float* out = (float*)d_out;

    char* ws = (char*)d_ws;
    ushort* xb      = (ushort*)ws;                                  // 2 MB
    float*  partAll = (float*)(ws + (2u << 20));                    // 512 KB
    float*  posBuf  = (float*)(ws + (2u << 20) + (512u << 10));     // 8 MB
    char*   meta    = ws + (11u << 20);
    int*    cntW    = (int*)meta;                                   // 32
    int*    posRank = (int*)(meta + 128);                           // 256
    int*    tileOff = (int*)(meta + 128 + 1024);                    // 256
    float*  partOut = (float*)(meta + 128 + 2048);                  // 256

    k_convert<<<1024, 256, 0, stream>>>(feats, labels, xb, cntW, posRank, tileOff);
    k_pass1  <<<1024, 256, 0, stream>>>(xb, labels, posRank, tileOff, partAll, posBuf);
    k_passB  <<<N_ANCH, 256, 0, stream>>>(posBuf, labels, cntW, posRank, tileOff, partAll, partOut);
    k_final  <<<1, 256, 0, stream>>>(partOut, out);
}

// Round 4
// 49.201 us; speedup vs baseline: 2.1525x; 1.2391x over previous
//
#include <hip/hip_runtime.h>
#include <hip/hip_bf16.h>

#define D_DIM   256
#define N_TOT   4096
#define N_ANCH  256
#define NSPLIT  32                    // pass1 column splits
#define COLS_PER 8                    // col anchors per block
#define NCHUNK  4                     // chunks of 2 anchors
#define K1  20.60992915555662f        // (1/0.07) * log2(e)
#define LN2 0.6931471805599453f
#define MAXNP    48                   // max anchors per label

typedef __attribute__((ext_vector_type(8))) short bf16x8;
typedef __attribute__((ext_vector_type(4))) float f32x4;

#define MFMA(a, b, c) __builtin_amdgcn_mfma_f32_16x16x32_bf16((a), (b), (c), 0, 0, 0)

__device__ __forceinline__ ushort f2bf(float f) {
    union { float f; unsigned u; } a; a.f = f;
    unsigned u = a.u;
    u = (u + 0x7FFFu + ((u >> 16) & 1u)) >> 16;   // RNE
    return (ushort)u;
}

// ---------- kernel 0: fp32 -> bf16 convert; block 0 also does label setup ----------
__global__ void __launch_bounds__(256) k_convert(const float* __restrict__ feats,
                                                 const int* __restrict__ labels,
                                                 ushort* __restrict__ xb,
                                                 int* __restrict__ cntW,
                                                 int* __restrict__ posRank,
                                                 int* __restrict__ tileOff) {
    int idx = blockIdx.x * 256 + threadIdx.x;
    int base = idx * 4;
    float4 v = *(const float4*)(feats + base);
    ushort4 o;
    o.x = f2bf(v.x); o.y = f2bf(v.y); o.z = f2bf(v.z); o.w = f2bf(v.w);
    *(ushort4*)(xb + base) = o;

    if (blockIdx.x == 0) {
        __shared__ int labS[N_ANCH];
        __shared__ int cntS[32];
        int t = threadIdx.x;
        if (t < 32) cntS[t] = 0;
        labS[t] = labels[t];
        __syncthreads();
        atomicAdd(&cntS[labS[t]], 1);
        __syncthreads();
        int myLab = labS[t];
        int rank = 0, toff = 0;
        for (int b = 0; b < t; ++b) {
            int lb = labS[b];
            rank += (lb == myLab);
            toff += cntS[lb];
        }
        posRank[t] = rank;
        tileOff[t] = toff;
        if (t < 32) cntW[t] = cntS[t];
    }
}

// ---------- kernel 1: LDS-staged fused GEMM sweep ----------
// 1024 blocks (32 row groups x 32 col splits), 4 waves.
// Wave owns 2 row anchors (A in regs, loaded via LDS staging).
// Col sweep: 8 anchors in 4 double-buffered chunks of 2 (16 KB each).
__global__ void __launch_bounds__(256, 4) k_pass1(const ushort* __restrict__ xb,
                                                  const int* __restrict__ labels,
                                                  const int* __restrict__ posRank,
                                                  const int* __restrict__ tileOff,
                                                  float* __restrict__ partAll,
                                                  float* __restrict__ posBuf) {
    __shared__ char ldsB[2][16384];
    char* ldsAll = &ldsB[0][0];            // 32 KB contiguous for A prologue

    int g = blockIdx.x >> 5;               // row group 0..31 (8 anchors)
    int s = blockIdx.x & 31;               // col split 0..31 (8 anchors)
    int tid = threadIdx.x;
    int wid = tid >> 6, lane = tid & 63;
    int lrow = lane & 15, khalf = lane >> 4;
    int rt0 = g * 8 + wid * 2, rt1 = rt0 + 1;

    const uint32_t swz  = (uint32_t)((lrow & 7) << 4);
    const uint32_t rbase = (uint32_t)(lrow * 512 + khalf * 16);
    int cbase = s * COLS_PER;

    // prefetch chunk 0 of B early (latency hidden under A prologue)
    bf16x8 st[4];
    const ushort* src0 = xb + cbase * 16 * D_DIM;
    #pragma unroll
    for (int o = 0; o < 4; ++o)
        st[o] = *(const bf16x8*)(src0 + tid * 8 + o * 2048);

    // ---- A prologue: stage 8 row-anchor tiles through LDS (2 rounds x 32 KB) ----
    bf16x8 a0[8], a1[8];
    for (int rd = 0; rd < 2; ++rd) {
        const ushort* asrc = xb + (g * 8 + rd * 4) * 16 * D_DIM;
        bf16x8 sa[8];
        #pragma unroll
        for (int o = 0; o < 8; ++o)
            sa[o] = *(const bf16x8*)(asrc + tid * 8 + o * 2048);
        __syncthreads();                   // readers of previous round done
        #pragma unroll
        for (int o = 0; o < 8; ++o) {
            uint32_t L = (uint32_t)(tid * 16 + o * 4096);
            *(bf16x8*)(ldsAll + (L ^ (((L >> 9) & 7u) << 4))) = sa[o];
        }
        __syncthreads();                   // A tiles ready
        if ((wid >> 1) == rd) {            // this wave's anchors live in this round
            uint32_t abase = (uint32_t)(((wid & 1) * 2) * 8192) + rbase;
            #pragma unroll
            for (int ks = 0; ks < 8; ++ks) {
                uint32_t oA = (abase + ks * 64) ^ swz;
                a0[ks] = *(const bf16x8*)(ldsAll + oA);
                a1[ks] = *(const bf16x8*)(ldsAll + (oA + 8192));
            }
        }
    }
    #pragma unroll
    for (int ks = 0; ks < 8; ++ks)
        asm volatile("" : "+v"(a0[ks]), "+v"(a1[ks]));

    // metadata (block/wave-uniform -> scalar regs)
    int lab0 = labels[rt0], lab1 = labels[rt1];
    int off0 = tileOff[rt0], off1 = tileOff[rt1];
    int labc[8], rankc[8];
    #pragma unroll
    for (int j = 0; j < 8; ++j) {
        labc[j]  = labels[cbase + j];
        rankc[j] = posRank[cbase + j];
    }

    float aAll0[4] = {0, 0, 0, 0}, aAll1[4] = {0, 0, 0, 0};

    // ---- main loop: 4 double-buffered chunks of 2 col anchors ----
    for (int c = 0; c < NCHUNK; ++c) {
        char* buf = ldsB[c & 1];
        __syncthreads();                   // buffer free (readers of c-2 done)
        #pragma unroll
        for (int o = 0; o < 4; ++o) {
            uint32_t L = (uint32_t)(tid * 16 + o * 4096);
            *(bf16x8*)(buf + (L ^ (((L >> 9) & 7u) << 4))) = st[o];
        }
        __syncthreads();                   // buffer ready
        if (c + 1 < NCHUNK) {              // issue next chunk's loads (hide under MFMA)
            const ushort* srcn = src0 + (c + 1) * 8192;
            #pragma unroll
            for (int o = 0; o < 4; ++o)
                st[o] = *(const bf16x8*)(srcn + tid * 8 + o * 2048);
        }

        f32x4 c00 = {0,0,0,0}, c01 = {0,0,0,0}, c10 = {0,0,0,0}, c11 = {0,0,0,0};
        #pragma unroll
        for (int ks = 0; ks < 8; ++ks) {
            uint32_t o0 = (rbase + (uint32_t)(ks * 64)) ^ swz;
            bf16x8 b0 = *(const bf16x8*)(buf + o0);
            bf16x8 b1 = *(const bf16x8*)(buf + (o0 + 8192));
            c00 = MFMA(a0[ks], b0, c00);
            c10 = MFMA(a1[ks], b0, c10);
            c01 = MFMA(a0[ks], b1, c01);
            c11 = MFMA(a1[ks], b1, c11);
        }

        int j0 = c * 2, j1 = j0 + 1;
        int aj0 = cbase + j0, aj1 = aj0 + 1;
        #pragma unroll
        for (int i = 0; i < 4; ++i) {
            aAll0[i] += exp2f(__builtin_fmaf(c00[i], K1, -K1))
                      + exp2f(__builtin_fmaf(c01[i], K1, -K1));
            aAll1[i] += exp2f(__builtin_fmaf(c10[i], K1, -K1))
                      + exp2f(__builtin_fmaf(c11[i], K1, -K1));
        }
        if (labc[j0] == lab0)
            *(f32x4*)(posBuf + (size_t)(off0 + rankc[j0]) * 256 + lane * 4) = c00;
        if (labc[j0] == lab1)
            *(f32x4*)(posBuf + (size_t)(off1 + rankc[j0]) * 256 + lane * 4) = c10;
        if (labc[j1] == lab0)
            *(f32x4*)(posBuf + (size_t)(off0 + rankc[j1]) * 256 + lane * 4) = c01;
        if (labc[j1] == lab1)
            *(f32x4*)(posBuf + (size_t)(off1 + rankc[j1]) * 256 + lane * 4) = c11;
        (void)aj0; (void)aj1;
    }

    // ---- reduce over the 16-lane column groups, store S_all partials ----
    #pragma unroll
    for (int m = 1; m < 16; m <<= 1) {
        #pragma unroll
        for (int i = 0; i < 4; ++i) {
            aAll0[i] += __shfl_xor(aAll0[i], m, 64);
            aAll1[i] += __shfl_xor(aAll1[i], m, 64);
        }
    }
    if (lrow == 0) {
        #pragma unroll
        for (int i = 0; i < 4; ++i) {
            int r0 = rt0 * 16 + khalf * 4 + i;
            int r1 = r0 + 16;
            partAll[r0 * NSPLIT + s] = aAll0[i];
            partAll[r1 * NSPLIT + s] = aAll1[i];
        }
    }
}

// ---------- kernel 2: elementwise positive pass ----------
__global__ void __launch_bounds__(256) k_passB(const float* __restrict__ posBuf,
                                               const int* __restrict__ labels,
                                               const int* __restrict__ cntW,
                                               const int* __restrict__ posRank,
                                               const int* __restrict__ tileOff,
                                               const float* __restrict__ partAll,
                                               float* __restrict__ partOut) {
    int rt  = blockIdx.x;
    int tid = threadIdx.x;
    int l = tid >> 2, i = tid & 3;
    int r   = (l >> 4) * 4 + i;        // row within tile (fixed per thread)
    int col = l & 15;

    int np       = cntW[labels[rt]];
    int off      = tileOff[rt];
    int selfRank = posRank[rt];

    __shared__ float tile[MAXNP * 256];
    __shared__ float shA[16][17];
    __shared__ float shB[16][17];
    __shared__ float nsSh[16], PSh[16];

    float sE = 0.f, sP = 0.f;
    const float* src = posBuf + (size_t)off * 256 + tid;
    for (int j = 0; j < np; ++j) {
        float c = src[j * 256];
        tile[j * 256 + tid] = c;
        float l2 = __builtin_fmaf(c, K1, -K1);
        sE += exp2f(l2);
        bool diag = (j == selfRank) & (col == r);
        sP += diag ? 0.f : l2;
    }
    shA[r][col] = sE;
    shB[r][col] = sP;
    __syncthreads();
    if (tid < 16) {
        float e = 0.f, p = 0.f;
        #pragma unroll
        for (int cc = 0; cc < 16; ++cc) { e += shA[tid][cc]; p += shB[tid][cc]; }
        const float* pa = partAll + (rt * 16 + tid) * NSPLIT;
        float sall = 0.f;
        #pragma unroll
        for (int q = 0; q < 8; ++q) {
            float4 v = *(const float4*)(pa + q * 4);
            sall += v.x + v.y + v.z + v.w;
        }
        nsSh[tid] = sall - e;          // negative-pair exp sum
        PSh[tid]  = p;
    }
    __syncthreads();

    float nsv = nsSh[r];
    float sL = 0.f;
    for (int j = 0; j < np; ++j) {
        float c  = tile[j * 256 + tid];
        float l2 = __builtin_fmaf(c, K1, -K1);
        float lg = __log2f(exp2f(l2) + nsv);
        bool diag = (j == selfRank) & (col == r);
        sL += diag ? 0.f : lg;
    }
    __syncthreads();
    shA[r][col] = sL;
    __syncthreads();
    if (tid < 16) {
        float L = 0.f;
        #pragma unroll
        for (int cc = 0; cc < 16; ++cc) L += shA[tid][cc];
        float npRow = (float)(16 * np - 1);
        shB[0][tid] = (PSh[tid] - L) / npRow;
    }
    __syncthreads();
    if (tid == 0) {
        float sx = 0.f;
        #pragma unroll
        for (int q = 0; q < 16; ++q) sx += shB[0][q];
        partOut[rt] = sx;
    }
}

// ---------- kernel 3: final reduction ----------
__global__ void __launch_bounds__(256) k_final(const float* __restrict__ partOut,
                                               float* __restrict__ out) {
    __shared__ float red[256];
    int t = threadIdx.x;
    red[t] = partOut[t];
    __syncthreads();
    for (int o = 128; o; o >>= 1) {
        if (t < o) red[t] += red[t + o];
        __syncthreads();
    }
    if (t == 0) out[0] = -red[0] * (LN2 / (float)N_TOT);
}

extern "C" void kernel_launch(void* const* d_in, const int* in_sizes, int n_in,
                              void* d_out, int out_size, void* d_ws, size_t ws_size,
                              hipStream_t stream) {
    const float* feats  = (const float*)d_in[0];
    const int*   labels = (const int*)d_in[1];
    float* out = (float*)d_out;

    char* ws = (char*)d_ws;
    ushort* xb      = (ushort*)ws;                                  // 2 MB
    float*  partAll = (float*)(ws + (2u << 20));                    // 512 KB
    float*  posBuf  = (float*)(ws + (2u << 20) + (512u << 10));     // 8 MB
    char*   meta    = ws + (11u << 20);
    int*    cntW    = (int*)meta;                                   // 32
    int*    posRank = (int*)(meta + 128);                           // 256
    int*    tileOff = (int*)(meta + 128 + 1024);                    // 256
    float*  partOut = (float*)(meta + 128 + 2048);                  // 256

    k_convert<<<1024, 256, 0, stream>>>(feats, labels, xb, cntW, posRank, tileOff);
    k_pass1  <<<1024, 256, 0, stream>>>(xb, labels, posRank, tileOff, partAll, posBuf);
    k_passB  <<<N_ANCH, 256, 0, stream>>>(posBuf, labels, cntW, posRank, tileOff, partAll, partOut);
    k_final  <<<1, 256, 0, stream>>>(partOut, out);
}

// Round 6
// 37.092 us; speedup vs baseline: 2.8552x; 1.3265x over previous
//
#include <hip/hip_runtime.h>
#include <hip/hip_bf16.h>

#define D_DIM   256
#define N_TOT   4096
#define N_ANCH  256
#define NCOLG   32                    // col groups (4096/128)
#define NPART   64                    // partAll slots per row = NCOLG * 2 (per-wave-col)
#define K1  20.60992915555662f        // (1/0.07) * log2(e)
#define LN2 0.6931471805599453f
#define MAXNP    48                   // max anchors per label

typedef __attribute__((ext_vector_type(8))) short bf16x8;
typedef __attribute__((ext_vector_type(4))) float f32x4;

#define MFMA(a, b, c) __builtin_amdgcn_mfma_f32_16x16x32_bf16((a), (b), (c), 0, 0, 0)

__device__ __forceinline__ ushort f2bf(float f) {
    union { float f; unsigned u; } a; a.f = f;
    unsigned u = a.u;
    u = (u + 0x7FFFu + ((u >> 16) & 1u)) >> 16;   // RNE
    return (ushort)u;
}

// ---------- kernel 0: fp32 -> bf16 convert; block 0 also does label setup ----------
__global__ void __launch_bounds__(256) k_convert(const float* __restrict__ feats,
                                                 const int* __restrict__ labels,
                                                 ushort* __restrict__ xb,
                                                 int* __restrict__ cntW,
                                                 int* __restrict__ posRank,
                                                 int* __restrict__ tileOff) {
    int idx = blockIdx.x * 256 + threadIdx.x;
    int base = idx * 4;
    float4 v = *(const float4*)(feats + base);
    ushort4 o;
    o.x = f2bf(v.x); o.y = f2bf(v.y); o.z = f2bf(v.z); o.w = f2bf(v.w);
    *(ushort4*)(xb + base) = o;

    if (blockIdx.x == 0) {
        __shared__ int labS[N_ANCH];
        __shared__ int cntS[32];
        int t = threadIdx.x;
        if (t < 32) cntS[t] = 0;
        labS[t] = labels[t];
        __syncthreads();
        atomicAdd(&cntS[labS[t]], 1);
        __syncthreads();
        int myLab = labS[t];
        int rank = 0, toff = 0;
        for (int b = 0; b < t; ++b) {
            int lb = labS[b];
            rank += (lb == myLab);
            toff += cntS[lb];
        }
        posRank[t] = rank;
        tileOff[t] = toff;
        if (t < 32) cntW[t] = cntS[t];
    }
}

// ---------- kernel 1: 128x128-tile fused GEMM sweep ----------
// 1024 blocks (32 row groups x 32 col groups), 256 threads = 4 waves (2x2).
// Each wave: 64x64 output = 4x4 fragments. K=256 in two BK=128 chunks
// through one 64 KB swizzled LDS buffer.
// partAll is indexed [row][s*2 + wc] so the two waves sharing rows never collide.
__global__ void __launch_bounds__(256, 2) k_pass1(const ushort* __restrict__ xb,
                                                  const int* __restrict__ labels,
                                                  const int* __restrict__ posRank,
                                                  const int* __restrict__ tileOff,
                                                  float* __restrict__ partAll,
                                                  float* __restrict__ posBuf) {
    __shared__ __align__(16) char lds[65536];   // A: [0,32K), B: [32K,64K)

    const int g = blockIdx.x >> 5;              // row group (8 anchors = 128 rows)
    const int s = blockIdx.x & 31;              // col group
    const int tid = threadIdx.x;
    const int lane = tid & 63, wid = tid >> 6;
    const int lrow = lane & 15, khalf = lane >> 4;
    const int wr = wid >> 1, wc = wid & 1;      // wave sub-tile (wr*64, wc*64)

    const char* aSrc = (const char*)(xb + (size_t)g * 128 * D_DIM);
    const char* bSrc = (const char*)(xb + (size_t)s * 128 * D_DIM);

    // staging address decode (8 x 16B per thread per operand per chunk)
    uint32_t Lg[8], Lw[8];
#pragma unroll
    for (int o = 0; o < 8; ++o) {
        uint32_t L = (uint32_t)(tid * 16 + o * 4096);      // linear LDS byte
        Lg[o] = (L >> 8) * 512 + (L & 255);                // global byte in chunk
        Lw[o] = L ^ (((L >> 8) & 7u) << 4);                // swizzled LDS byte
    }

    bf16x8 stA[8], stB[8];
    auto loadch = [&](int kc) {
#pragma unroll
        for (int o = 0; o < 8; ++o) {
            stA[o] = *(const bf16x8*)(aSrc + Lg[o] + kc * 256);
            stB[o] = *(const bf16x8*)(bSrc + Lg[o] + kc * 256);
        }
    };
    auto writelds = [&]() {
#pragma unroll
        for (int o = 0; o < 8; ++o) {
            *(bf16x8*)(lds + Lw[o])         = stA[o];
            *(bf16x8*)(lds + 32768 + Lw[o]) = stB[o];
        }
    };

    f32x4 acc[4][4];
#pragma unroll
    for (int m = 0; m < 4; ++m)
#pragma unroll
        for (int n = 0; n < 4; ++n)
            acc[m][n] = (f32x4){0.f, 0.f, 0.f, 0.f};

    const uint32_t swz = (uint32_t)((lrow & 7) << 4);
    auto compute = [&]() {
#pragma unroll
        for (int ks = 0; ks < 4; ++ks) {
            bf16x8 af[4], bfr[4];
#pragma unroll
            for (int m = 0; m < 4; ++m) {
                uint32_t row = (uint32_t)(wr * 64 + m * 16 + lrow);
                af[m] = *(const bf16x8*)(lds + ((row * 256 + ks * 64 + khalf * 16) ^ swz));
            }
#pragma unroll
            for (int n = 0; n < 4; ++n) {
                uint32_t row = (uint32_t)(wc * 64 + n * 16 + lrow);
                bfr[n] = *(const bf16x8*)(lds + 32768 + ((row * 256 + ks * 64 + khalf * 16) ^ swz));
            }
#pragma unroll
            for (int m = 0; m < 4; ++m)
#pragma unroll
                for (int n = 0; n < 4; ++n)
                    acc[m][n] = MFMA(af[m], bfr[n], acc[m][n]);
        }
    };

    loadch(0);
    writelds();
    __syncthreads();        // chunk 0 ready
    loadch(1);              // prefetch chunk 1 (hides under compute)
    compute();
    __syncthreads();        // all reads of chunk 0 done
    writelds();
    __syncthreads();        // chunk 1 ready
    compute();

    // ---- epilogue: exp2 row sums + positive-tile stores ----
    const int raBase = g * 8 + wr * 4, caBase = s * 8 + wc * 4;
    int labR[4], offR[4], labC[4], rankC[4];
#pragma unroll
    for (int m = 0; m < 4; ++m) {
        labR[m] = labels[raBase + m];
        offR[m] = tileOff[raBase + m];
    }
#pragma unroll
    for (int n = 0; n < 4; ++n) {
        labC[n] = labels[caBase + n];
        rankC[n] = posRank[caBase + n];
    }

    float aAll[4][4];       // [row-frag m][i]
#pragma unroll
    for (int m = 0; m < 4; ++m)
#pragma unroll
        for (int i = 0; i < 4; ++i) aAll[m][i] = 0.f;

#pragma unroll
    for (int m = 0; m < 4; ++m) {
#pragma unroll
        for (int n = 0; n < 4; ++n) {
            f32x4 c = acc[m][n];
#pragma unroll
            for (int i = 0; i < 4; ++i)
                aAll[m][i] += exp2f(__builtin_fmaf(c[i], K1, -K1));
            if (labR[m] == labC[n])    // wave-uniform: store raw scores for passB
                *(f32x4*)(posBuf + (size_t)(offR[m] + rankC[n]) * 256 + lane * 4) = c;
        }
    }

#pragma unroll
    for (int msk = 1; msk < 16; msk <<= 1)
#pragma unroll
        for (int m = 0; m < 4; ++m)
#pragma unroll
            for (int i = 0; i < 4; ++i)
                aAll[m][i] += __shfl_xor(aAll[m][i], msk, 64);

    if (lrow == 0) {
#pragma unroll
        for (int m = 0; m < 4; ++m)
#pragma unroll
            for (int i = 0; i < 4; ++i) {
                int row = g * 128 + wr * 64 + m * 16 + khalf * 4 + i;
                partAll[row * NPART + s * 2 + wc] = aAll[m][i];
            }
    }
}

// ---------- kernel 2: elementwise positive pass ----------
__global__ void __launch_bounds__(256) k_passB(const float* __restrict__ posBuf,
                                               const int* __restrict__ labels,
                                               const int* __restrict__ cntW,
                                               const int* __restrict__ posRank,
                                               const int* __restrict__ tileOff,
                                               const float* __restrict__ partAll,
                                               float* __restrict__ partOut) {
    int rt  = blockIdx.x;
    int tid = threadIdx.x;
    int l = tid >> 2, i = tid & 3;
    int r   = (l >> 4) * 4 + i;        // row within tile (fixed per thread)
    int col = l & 15;

    int np       = cntW[labels[rt]];
    int off      = tileOff[rt];
    int selfRank = posRank[rt];

    __shared__ float tile[MAXNP * 256];
    __shared__ float shA[16][17];
    __shared__ float shB[16][17];
    __shared__ float nsSh[16], PSh[16];

    float sE = 0.f, sP = 0.f;
    const float* src = posBuf + (size_t)off * 256 + tid;
    for (int j = 0; j < np; ++j) {
        float c = src[j * 256];
        tile[j * 256 + tid] = c;
        float l2 = __builtin_fmaf(c, K1, -K1);
        sE += exp2f(l2);
        bool diag = (j == selfRank) & (col == r);
        sP += diag ? 0.f : l2;
    }
    shA[r][col] = sE;
    shB[r][col] = sP;
    __syncthreads();
    if (tid < 16) {
        float e = 0.f, p = 0.f;
#pragma unroll
        for (int cc = 0; cc < 16; ++cc) { e += shA[tid][cc]; p += shB[tid][cc]; }
        const float* pa = partAll + (rt * 16 + tid) * NPART;
        float sall = 0.f;
#pragma unroll
        for (int q = 0; q < 16; ++q) {
            float4 v = *(const float4*)(pa + q * 4);
            sall += v.x + v.y + v.z + v.w;
        }
        nsSh[tid] = sall - e;          // negative-pair exp sum
        PSh[tid]  = p;
    }
    __syncthreads();

    float nsv = nsSh[r];
    float sL = 0.f;
    for (int j = 0; j < np; ++j) {
        float c  = tile[j * 256 + tid];
        float l2 = __builtin_fmaf(c, K1, -K1);
        float lg = __log2f(exp2f(l2) + nsv);
        bool diag = (j == selfRank) & (col == r);
        sL += diag ? 0.f : lg;
    }
    __syncthreads();
    shA[r][col] = sL;
    __syncthreads();
    if (tid < 16) {
        float L = 0.f;
#pragma unroll
        for (int cc = 0; cc < 16; ++cc) L += shA[tid][cc];
        float npRow = (float)(16 * np - 1);
        shB[0][tid] = (PSh[tid] - L) / npRow;
    }
    __syncthreads();
    if (tid == 0) {
        float sx = 0.f;
#pragma unroll
        for (int q = 0; q < 16; ++q) sx += shB[0][q];
        partOut[rt] = sx;
    }
}

// ---------- kernel 3: final reduction ----------
__global__ void __launch_bounds__(256) k_final(const float* __restrict__ partOut,
                                               float* __restrict__ out) {
    __shared__ float red[256];
    int t = threadIdx.x;
    red[t] = partOut[t];
    __syncthreads();
    for (int o = 128; o; o >>= 1) {
        if (t < o) red[t] += red[t + o];
        __syncthreads();
    }
    if (t == 0) out[0] = -red[0] * (LN2 / (float)N_TOT);
}

extern "C" void kernel_launch(void* const* d_in, const int* in_sizes, int n_in,
                              void* d_out, int out_size, void* d_ws, size_t ws_size,
                              hipStream_t stream) {
    const float* feats  = (const float*)d_in[0];
    const int*   labels = (const int*)d_in[1];
    float* out = (float*)d_out;

    char* ws = (char*)d_ws;
    ushort* xb      = (ushort*)ws;                                  // 2 MB
    float*  partAll = (float*)(ws + (2u << 20));                    // 1 MB (4096*64 f32)
    float*  posBuf  = (float*)(ws + (3u << 20));                    // 8 MB
    char*   meta    = ws + (11u << 20);
    int*    cntW    = (int*)meta;                                   // 32
    int*    posRank = (int*)(meta + 128);                           // 256
    int*    tileOff = (int*)(meta + 128 + 1024);                    // 256
    float*  partOut = (float*)(meta + 128 + 2048);                  // 256

    k_convert<<<1024, 256, 0, stream>>>(feats, labels, xb, cntW, posRank, tileOff);
    k_pass1  <<<1024, 256, 0, stream>>>(xb, labels, posRank, tileOff, partAll, posBuf);
    k_passB  <<<N_ANCH, 256, 0, stream>>>(posBuf, labels, cntW, posRank, tileOff, partAll, partOut);
    k_final  <<<1, 256, 0, stream>>>(partOut, out);
}